// Round 4
// baseline (179.498 us; speedup 1.0000x reference)
//
#include <hip/hip_runtime.h>

// x [B=16, N=1024, F=256] fp32.  Algebra (alpha folded away):
//   Wab = Wa^T @ Wb  (prep, bf16)          Wcb = bf16(Wr@Wu); bc = Wr@bu
//   ab  = x @ Wab^T   (proj)               U2 = x @ Wcb^T + bc
//   d[m] = x[m]·ab[m] (diag term; == alpha[m]·beta[m])
//   G[b][j][f] = sum_i U2[b,i,j] * ab[b,i,f]      (F x F per batch)
//   out[m,j] = (x[m,:]·G[b][j,:] - d[m]*U2[m,j]) / N + x[m,j]
// Round-4: BARRIER-FREE main loops.  R3 counters: MfmaUtil 3%, 97% stall --
// hipcc drains vmcnt(0) before every s_barrier, so LDS-staged loops expose a
// full memory round-trip per K-step.  Here every wave owns distinct output
// rows and B operands are L1/L2-hot, so A and B fragments are loaded per-lane
// DIRECTLY from global in MFMA layout: no LDS, no __syncthreads in any main
// loop.  LDS only in proj's one-time transpose epilogue.

typedef __bf16 bf16;
typedef float floatx4 __attribute__((ext_vector_type(4)));
typedef bf16 bf16x8 __attribute__((ext_vector_type(8)));
typedef bf16 bf16x4 __attribute__((ext_vector_type(4)));

constexpr int FD = 256;
constexpr int NB = 16;
constexpr int NN = 1024;
constexpr int RR = NB * NN;   // 16384

__device__ __forceinline__ bf16x8 cvt8(float4 a, float4 b) {
    bf16x8 o = { (bf16)a.x, (bf16)a.y, (bf16)a.z, (bf16)a.w,
                 (bf16)b.x, (bf16)b.y, (bf16)b.z, (bf16)b.w };
    return o;
}

// ---------------- K1: prep ----------------
__global__ __launch_bounds__(256)
void prep(const float* __restrict__ Wa, const float* __restrict__ Wb,
          const float* __restrict__ Wu, const float* __restrict__ bu,
          const float* __restrict__ Wr,
          bf16* __restrict__ Wcb, bf16* __restrict__ Wab, float* __restrict__ bc)
{
    const int blk = blockIdx.x, tid = threadIdx.x;
    if (blk < 256) {  // Wcb[j][f] = sum_g Wr[j][g]*Wu[g][f]; one j per block
        const int j = blk;
        float acc = 0.0f;
        for (int g = 0; g < FD; g += 4) {
            float4 wr = *(const float4*)&Wr[j * FD + g];
            acc += wr.x * Wu[g * FD + tid] + wr.y * Wu[(g + 1) * FD + tid]
                 + wr.z * Wu[(g + 2) * FD + tid] + wr.w * Wu[(g + 3) * FD + tid];
        }
        Wcb[j * FD + tid] = (bf16)acc;
    } else if (blk == 256) {  // bc[j] = Wr[j,:].bu
        float s = 0.0f;
        for (int g = 0; g < FD; g++) s += Wr[tid * FD + g] * bu[g];
        bc[tid] = s;
    } else {  // Wab[f][g] = sum_k Wa[k][f]*Wb[k][g]; one f per block
        const int f = blk - 257;
        float acc = 0.0f;
        for (int k = 0; k < FD; k += 4) {
            acc += Wa[k * FD + f] * Wb[k * FD + tid]
                 + Wa[(k + 1) * FD + f] * Wb[(k + 1) * FD + tid]
                 + Wa[(k + 2) * FD + f] * Wb[(k + 2) * FD + tid]
                 + Wa[(k + 3) * FD + f] * Wb[(k + 3) * FD + tid];
        }
        Wab[f * FD + tid] = (bf16)acc;
    }
}

// ---------------- K2: proj (barrier-free main loop; per-lane direct fragments) ----------------
// block = 4 waves x 16 rows = 64 rows (bm), 64 cols (bn); grid (4, 256)
__global__ __launch_bounds__(256, 3)
void proj(const float* __restrict__ x,
          const bf16* __restrict__ Wab, const bf16* __restrict__ Wc,
          bf16* __restrict__ U2, bf16* __restrict__ abT, bf16* __restrict__ U2T,
          const float* __restrict__ bc, float* __restrict__ dpart)
{
    __shared__ __align__(16) bf16 Tr[64 * 72];   // epilogue transpose only
    const int tid = threadIdx.x;
    const int wave = tid >> 6, lane = tid & 63;
    const int q = lane >> 4, l16 = lane & 15;
    const int bm = blockIdx.y * 64, bn = blockIdx.x * 64;

    const float* xr  = x   + (size_t)(bm + wave * 16 + l16) * FD;  // A row (per lane)
    const bf16*  wa0 = Wab + (size_t)(bn + l16) * FD;              // B rows (nj via +nj*16*FD)
    const bf16*  wc0 = Wc  + (size_t)(bn + l16) * FD;

    floatx4 acc[2][4] = {};   // [plane][nj]; plane0=ab, plane1=U2
    #pragma unroll
    for (int k0 = 0; k0 < FD; k0 += 32) {
        const int ko = k0 + q * 8;
        bf16x8 af = cvt8(*(const float4*)&xr[ko], *(const float4*)&xr[ko + 4]);
        #pragma unroll
        for (int nj = 0; nj < 4; nj++) {
            bf16x8 b0 = *(const bf16x8*)&wa0[(size_t)nj * 16 * FD + ko];
            bf16x8 b1 = *(const bf16x8*)&wc0[(size_t)nj * 16 * FD + ko];
            acc[0][nj] = __builtin_amdgcn_mfma_f32_16x16x32_bf16(af, b0, acc[0][nj], 0, 0, 0);
            acc[1][nj] = __builtin_amdgcn_mfma_f32_16x16x32_bf16(af, b1, acc[1][nj], 0, 0, 0);
        }
    }

    const int b = bm >> 10, n0 = bm & (NN - 1);
    float bcv[4];
    #pragma unroll
    for (int nj = 0; nj < 4; nj++) bcv[nj] = bc[bn + nj * 16 + l16];

    // diag partials: d[m] (this tile's 64 f-cols) = sum_f x[m,f]*ab[m,f]
    #pragma unroll
    for (int i = 0; i < 4; i++) {
        const int m = bm + wave * 16 + q * 4 + i;
        float p = 0.0f;
        #pragma unroll
        for (int nj = 0; nj < 4; nj++)
            p += x[(size_t)m * FD + bn + nj * 16 + l16] * acc[0][nj][i];
        #pragma unroll
        for (int off = 1; off < 16; off <<= 1) p += __shfl_xor(p, off);
        if (l16 == 0) dpart[(size_t)blockIdx.x * RR + m] = p;
    }

    // natural output via Tr[64][72]: U2 (+bc)
    #pragma unroll
    for (int i = 0; i < 4; i++) {
        int ml = wave * 16 + q * 4 + i;
        #pragma unroll
        for (int nj = 0; nj < 4; nj++)
            Tr[ml * 72 + nj * 16 + l16] = (bf16)(acc[1][nj][i] + bcv[nj]);
    }
    __syncthreads();
    #pragma unroll
    for (int it = 0; it < 2; it++) {
        int c = tid + it * 256;
        int r = c >> 3, chunk = c & 7;
        bf16x8 v = *(const bf16x8*)&Tr[r * 72 + chunk * 8];
        *(bf16x8*)&U2[(size_t)(bm + r) * FD + bn + chunk * 8] = v;
    }

    // transposed outputs via Tr[64][72]: abT (pass 0), U2T (pass 1, +bc)
    #pragma unroll
    for (int pass = 0; pass < 2; pass++) {
        __syncthreads();
        #pragma unroll
        for (int nj = 0; nj < 4; nj++) {
            bf16x4 v4;
            #pragma unroll
            for (int i = 0; i < 4; i++) {
                float v = acc[pass][nj][i];
                if (pass == 1) v += bcv[nj];
                v4[i] = (bf16)v;
            }
            *(bf16x4*)&Tr[(nj * 16 + l16) * 72 + wave * 16 + q * 4] = v4;
        }
        __syncthreads();
        bf16* dst = (pass ? U2T : abT) + (size_t)b * FD * NN;
        #pragma unroll
        for (int it = 0; it < 2; it++) {
            int c = tid + it * 256;
            int r = c >> 3, chunk = c & 7;
            bf16x8 v = *(const bf16x8*)&Tr[r * 72 + chunk * 8];
            *(bf16x8*)&dst[(size_t)(bn + r) * NN + n0 + chunk * 8] = v;
        }
    }
}

// ---------------- K3: G[b][j][k] = sum_n U2T[b][j][n]*abT[b][k][n] ----------------
// block = 64j x 32k, 4 waves x 16j; grid (8 k-tiles, 4 j-tiles, 16 b). No LDS, no barriers.
__global__ __launch_bounds__(256, 2)
void m2_mfma(const bf16* __restrict__ U2T, const bf16* __restrict__ abT, bf16* __restrict__ G)
{
    const int tid = threadIdx.x;
    const int wave = tid >> 6, lane = tid & 63;
    const int q = lane >> 4, l16 = lane & 15;
    const int b = blockIdx.z;
    const int bj = blockIdx.y * 64, bk = blockIdx.x * 32;

    const bf16* ar = U2T + (size_t)b * FD * NN + (size_t)(bj + wave * 16 + l16) * NN;
    const bf16* b0 = abT + (size_t)b * FD * NN + (size_t)(bk + l16) * NN;
    const bf16* b1 = b0 + (size_t)16 * NN;

    floatx4 acc[2] = {};
    #pragma unroll 4
    for (int n0 = 0; n0 < NN; n0 += 32) {
        const int no = n0 + q * 8;
        bf16x8 af  = *(const bf16x8*)&ar[no];
        bf16x8 bq0 = *(const bf16x8*)&b0[no];
        bf16x8 bq1 = *(const bf16x8*)&b1[no];
        acc[0] = __builtin_amdgcn_mfma_f32_16x16x32_bf16(af, bq0, acc[0], 0, 0, 0);
        acc[1] = __builtin_amdgcn_mfma_f32_16x16x32_bf16(af, bq1, acc[1], 0, 0, 0);
    }

    bf16* Gb = G + (size_t)b * FD * FD;
    #pragma unroll
    for (int i = 0; i < 4; i++) {
        const int j = bj + wave * 16 + q * 4 + i;
        #pragma unroll
        for (int kj = 0; kj < 2; kj++)
            Gb[(size_t)j * FD + bk + kj * 16 + l16] = (bf16)acc[kj][i];
    }
}

// ---------------- K4: out = (x_bf @ G[b]^T(NT) - d*U2)/N + x ----------------
// block = 4 waves x 16 rows = 64 rows, 64 cols; grid (4, 256). No LDS, no barriers.
__global__ __launch_bounds__(256, 4)
void final_mfma(const float* __restrict__ x, const bf16* __restrict__ G,
                const float* __restrict__ dpart, const bf16* __restrict__ U2,
                float* __restrict__ out)
{
    const int tid = threadIdx.x;
    const int wave = tid >> 6, lane = tid & 63;
    const int q = lane >> 4, l16 = lane & 15;
    const int bm = blockIdx.y * 64, bn = blockIdx.x * 64;

    const float* xr = x + (size_t)(bm + wave * 16 + l16) * FD;
    const bf16*  g0 = G + (size_t)(bm >> 10) * FD * FD + (size_t)(bn + l16) * FD;

    floatx4 acc[4] = {};
    #pragma unroll
    for (int k0 = 0; k0 < FD; k0 += 32) {
        const int ko = k0 + q * 8;
        bf16x8 af = cvt8(*(const float4*)&xr[ko], *(const float4*)&xr[ko + 4]);
        #pragma unroll
        for (int nj = 0; nj < 4; nj++) {
            bf16x8 bq = *(const bf16x8*)&g0[(size_t)nj * 16 * FD + ko];
            acc[nj] = __builtin_amdgcn_mfma_f32_16x16x32_bf16(af, bq, acc[nj], 0, 0, 0);
        }
    }

    #pragma unroll
    for (int i = 0; i < 4; i++) {
        const int m = bm + wave * 16 + q * 4 + i;
        float d = dpart[m] + dpart[RR + m] + dpart[2 * RR + m] + dpart[3 * RR + m];
        #pragma unroll
        for (int nj = 0; nj < 4; nj++) {
            const int n = bn + nj * 16 + l16;
            float v = (acc[nj][i] - d * (float)U2[(size_t)m * FD + n]) * (1.0f / 1024.0f);
            out[(size_t)m * FD + n] = v + x[(size_t)m * FD + n];
        }
    }
}

extern "C" void kernel_launch(void* const* d_in, const int* in_sizes, int n_in,
                              void* d_out, int out_size, void* d_ws, size_t ws_size,
                              hipStream_t stream)
{
    const float* x  = (const float*)d_in[0];
    const float* Wa = (const float*)d_in[1];
    const float* Wb = (const float*)d_in[2];
    const float* Wu = (const float*)d_in[3];
    const float* bu = (const float*)d_in[4];
    const float* Wr = (const float*)d_in[5];
    float* out = (float*)d_out;

    char* w = (char*)d_ws;
    bf16* Wcb   = (bf16*)w;  w += (size_t)FD * FD * 2;
    bf16* Wab   = (bf16*)w;  w += (size_t)FD * FD * 2;
    float* bc   = (float*)w; w += (size_t)FD * 4;
    bf16* U2    = (bf16*)w;  w += (size_t)RR * FD * 2;
    bf16* abT   = (bf16*)w;  w += (size_t)RR * FD * 2;
    bf16* U2T   = (bf16*)w;  w += (size_t)RR * FD * 2;
    bf16* G     = (bf16*)w;  w += (size_t)NB * FD * FD * 2;
    float* dpart= (float*)w; w += (size_t)4 * RR * 4;

    dim3 blk(256);

    prep<<<dim3(513), blk, 0, stream>>>(Wa, Wb, Wu, bu, Wr, Wcb, Wab, bc);

    proj<<<dim3(4, 256), blk, 0, stream>>>(x, Wab, Wcb, U2, abT, U2T, bc, dpart);

    m2_mfma<<<dim3(8, 4, 16), blk, 0, stream>>>(U2T, abT, G);

    final_mfma<<<dim3(4, 256), blk, 0, stream>>>(x, G, dpart, U2, out);
}

// Round 5
// 162.778 us; speedup vs baseline: 1.1027x; 1.1027x over previous
//
#include <hip/hip_runtime.h>

// x [B=16, N=1024, F=256] fp32.  Algebra (alpha folded away):
//   WfA = pack(Wa^T @ Wb), WfC = pack(Wr@Wu), bc = Wr@bu   (prep; MFMA-fragment-packed)
//   ab  = x @ Wab^T   (proj)               U2 = x @ Wcb^T + bc
//   d[m] = x[m]·ab[m] (diag term)
//   G[b][j][f] = sum_i U2[b,i,j] * ab[b,i,f]
//   out[m,j] = (x[m,:]·G[b][j,:] - d[m]*U2[m,j]) / N + x[m,j]
// Round-5: proj re-tiled to 16-row x 256-col strips (grid 1024, 4 blocks/CU):
//   x fetched exactly ONCE (FETCH 37->~18MB), diag d[m] finished in-block,
//   B operands streamed from fragment-packed weights (1KB coalesced bursts,
//   L2-hot).  m2/final unchanged from R4 (clean attribution), final reads dvec.

typedef __bf16 bf16;
typedef float floatx4 __attribute__((ext_vector_type(4)));
typedef bf16 bf16x8 __attribute__((ext_vector_type(8)));

constexpr int FD = 256;
constexpr int NB = 16;
constexpr int NN = 1024;
constexpr int RR = NB * NN;   // 16384

__device__ __forceinline__ bf16x8 cvt8(float4 a, float4 b) {
    bf16x8 o = { (bf16)a.x, (bf16)a.y, (bf16)a.z, (bf16)a.w,
                 (bf16)b.x, (bf16)b.y, (bf16)b.z, (bf16)b.w };
    return o;
}

// fragment-packed index for a [256][256] B-operand consumed as 16-row frags,
// k-octets: chunk (f16,g32) is 1KB, lane = ((g>>3)&3)*16 + (f&15), elems g&7.
__device__ __forceinline__ int pk(int f, int g) {
    return ((f >> 4) * 8 + (g >> 5)) * 512 + (((g >> 3) & 3) * 16 + (f & 15)) * 8 + (g & 7);
}

// ---------------- K1: prep ----------------
__global__ __launch_bounds__(256)
void prep(const float* __restrict__ Wa, const float* __restrict__ Wb,
          const float* __restrict__ Wu, const float* __restrict__ bu,
          const float* __restrict__ Wr,
          bf16* __restrict__ WfC, bf16* __restrict__ WfA, float* __restrict__ bc)
{
    const int blk = blockIdx.x, tid = threadIdx.x;
    if (blk < 256) {  // Wcb[j][f] = sum_g Wr[j][g]*Wu[g][f]; one j per block
        const int j = blk;
        float acc = 0.0f;
        for (int g = 0; g < FD; g += 4) {
            float4 wr = *(const float4*)&Wr[j * FD + g];
            acc += wr.x * Wu[g * FD + tid] + wr.y * Wu[(g + 1) * FD + tid]
                 + wr.z * Wu[(g + 2) * FD + tid] + wr.w * Wu[(g + 3) * FD + tid];
        }
        WfC[pk(j, tid)] = (bf16)acc;
    } else if (blk == 256) {  // bc[j] = Wr[j,:].bu
        float s = 0.0f;
        for (int g = 0; g < FD; g++) s += Wr[tid * FD + g] * bu[g];
        bc[tid] = s;
    } else {  // Wab[f][g] = sum_k Wa[k][f]*Wb[k][g]; one f per block
        const int f = blk - 257;
        float acc = 0.0f;
        for (int k = 0; k < FD; k += 4) {
            acc += Wa[k * FD + f] * Wb[k * FD + tid]
                 + Wa[(k + 1) * FD + f] * Wb[(k + 1) * FD + tid]
                 + Wa[(k + 2) * FD + f] * Wb[(k + 2) * FD + tid]
                 + Wa[(k + 3) * FD + f] * Wb[(k + 3) * FD + tid];
        }
        WfA[pk(f, tid)] = (bf16)acc;
    }
}

// ---------------- K2: proj (16-row strip x 256 cols; x read once; packed B) ----------------
// block = 256 thr = 4 waves; wave w owns col-quarter [w*64, w*64+64). grid 1024.
__global__ __launch_bounds__(256, 4)
void proj(const float* __restrict__ x,
          const bf16* __restrict__ WfA, const bf16* __restrict__ WfC,
          bf16* __restrict__ U2, bf16* __restrict__ abT, bf16* __restrict__ U2T,
          const float* __restrict__ bc, float* __restrict__ dvec)
{
    __shared__ __align__(16) bf16 Tr16[16 * 264];   // natural repack [16 rows][256+8]
    __shared__ __align__(16) bf16 TrT[256 * 24];    // transposed repack [256 f][16+8]
    __shared__ float dsum[4][16];

    const int tid = threadIdx.x;
    const int wave = tid >> 6, lane = tid & 63;
    const int q = lane >> 4, l16 = lane & 15;
    const int bm = blockIdx.x * 16;
    const int b = bm >> 10, n0 = bm & (NN - 1);

    // A: whole K in registers; lane l16 <-> row, q <-> k-octet
    const float* xr = x + (size_t)(bm + l16) * FD;
    bf16x8 af[8];
    #pragma unroll
    for (int ks = 0; ks < 8; ks++) {
        const float* p = xr + ks * 32 + q * 8;
        af[ks] = cvt8(*(const float4*)p, *(const float4*)(p + 4));
    }

    floatx4 acc[2][4] = {};   // [plane][nj]; plane0=ab, plane1=U2
    #pragma unroll
    for (int nj = 0; nj < 4; nj++) {
        const bf16* pA = WfA + (size_t)((wave * 4 + nj) * 8) * 512 + lane * 8;
        const bf16* pC = WfC + (size_t)((wave * 4 + nj) * 8) * 512 + lane * 8;
        #pragma unroll
        for (int ks = 0; ks < 8; ks++) {
            bf16x8 b0 = *(const bf16x8*)(pA + ks * 512);
            bf16x8 b1 = *(const bf16x8*)(pC + ks * 512);
            acc[0][nj] = __builtin_amdgcn_mfma_f32_16x16x32_bf16(af[ks], b0, acc[0][nj], 0, 0, 0);
            acc[1][nj] = __builtin_amdgcn_mfma_f32_16x16x32_bf16(af[ks], b1, acc[1][nj], 0, 0, 0);
        }
    }

    // diag: d[m] = sum_f x[m,f]*ab[m,f]; quarter-partials -> LDS -> single write
    float pq[4];
    #pragma unroll
    for (int i = 0; i < 4; i++) {
        const int m = bm + q * 4 + i;
        float p = 0.0f;
        #pragma unroll
        for (int nj = 0; nj < 4; nj++)
            p += x[(size_t)m * FD + wave * 64 + nj * 16 + l16] * acc[0][nj][i];
        #pragma unroll
        for (int off = 1; off < 16; off <<= 1) p += __shfl_xor(p, off);
        pq[i] = p;
    }
    if (l16 == 0) {
        #pragma unroll
        for (int i = 0; i < 4; i++) dsum[wave][q * 4 + i] = pq[i];
    }

    float bcv[4];
    #pragma unroll
    for (int nj = 0; nj < 4; nj++) bcv[nj] = bc[wave * 64 + nj * 16 + l16];

    // natural U2 (+bc) via Tr16
    #pragma unroll
    for (int i = 0; i < 4; i++)
        #pragma unroll
        for (int nj = 0; nj < 4; nj++)
            Tr16[(q * 4 + i) * 264 + wave * 64 + nj * 16 + l16] = (bf16)(acc[1][nj][i] + bcv[nj]);
    __syncthreads();
    if (tid < 16) dvec[bm + tid] = dsum[0][tid] + dsum[1][tid] + dsum[2][tid] + dsum[3][tid];
    #pragma unroll
    for (int it = 0; it < 2; it++) {
        int c = tid + it * 256;
        int row = c >> 5, ch = c & 31;
        *(bf16x8*)&U2[(size_t)(bm + row) * FD + ch * 8] = *(const bf16x8*)&Tr16[row * 264 + ch * 8];
    }

    // transposed abT (pass 0), U2T (pass 1, +bc) via TrT
    #pragma unroll
    for (int pass = 0; pass < 2; pass++) {
        __syncthreads();
        #pragma unroll
        for (int nj = 0; nj < 4; nj++)
            #pragma unroll
            for (int i = 0; i < 4; i++) {
                float v = acc[pass][nj][i];
                if (pass == 1) v += bcv[nj];
                TrT[(wave * 64 + nj * 16 + l16) * 24 + q * 4 + i] = (bf16)v;
            }
        __syncthreads();
        bf16* dst = (pass ? U2T : abT) + (size_t)b * FD * NN;
        #pragma unroll
        for (int it = 0; it < 2; it++) {
            int c = tid + it * 256;
            int r = c >> 1, h = c & 1;
            *(bf16x8*)&dst[(size_t)r * NN + n0 + h * 8] = *(const bf16x8*)&TrT[r * 24 + h * 8];
        }
    }
}

// ---------------- K3: G[b][j][k] = sum_n U2T[b][j][n]*abT[b][k][n]  (unchanged R4) ----------------
__global__ __launch_bounds__(256, 2)
void m2_mfma(const bf16* __restrict__ U2T, const bf16* __restrict__ abT, bf16* __restrict__ G)
{
    const int tid = threadIdx.x;
    const int wave = tid >> 6, lane = tid & 63;
    const int q = lane >> 4, l16 = lane & 15;
    const int b = blockIdx.z;
    const int bj = blockIdx.y * 64, bk = blockIdx.x * 32;

    const bf16* ar = U2T + (size_t)b * FD * NN + (size_t)(bj + wave * 16 + l16) * NN;
    const bf16* b0 = abT + (size_t)b * FD * NN + (size_t)(bk + l16) * NN;
    const bf16* b1 = b0 + (size_t)16 * NN;

    floatx4 acc[2] = {};
    #pragma unroll 4
    for (int n0 = 0; n0 < NN; n0 += 32) {
        const int no = n0 + q * 8;
        bf16x8 af  = *(const bf16x8*)&ar[no];
        bf16x8 bq0 = *(const bf16x8*)&b0[no];
        bf16x8 bq1 = *(const bf16x8*)&b1[no];
        acc[0] = __builtin_amdgcn_mfma_f32_16x16x32_bf16(af, bq0, acc[0], 0, 0, 0);
        acc[1] = __builtin_amdgcn_mfma_f32_16x16x32_bf16(af, bq1, acc[1], 0, 0, 0);
    }

    bf16* Gb = G + (size_t)b * FD * FD;
    #pragma unroll
    for (int i = 0; i < 4; i++) {
        const int j = bj + wave * 16 + q * 4 + i;
        #pragma unroll
        for (int kj = 0; kj < 2; kj++)
            Gb[(size_t)j * FD + bk + kj * 16 + l16] = (bf16)acc[kj][i];
    }
}

// ---------------- K4: out = (x_bf @ G[b]^T(NT) - d*U2)/N + x  (R4 + dvec) ----------------
__global__ __launch_bounds__(256, 4)
void final_mfma(const float* __restrict__ x, const bf16* __restrict__ G,
                const float* __restrict__ dvec, const bf16* __restrict__ U2,
                float* __restrict__ out)
{
    const int tid = threadIdx.x;
    const int wave = tid >> 6, lane = tid & 63;
    const int q = lane >> 4, l16 = lane & 15;
    const int bm = blockIdx.y * 64, bn = blockIdx.x * 64;

    const float* xr = x + (size_t)(bm + wave * 16 + l16) * FD;
    const bf16*  g0 = G + (size_t)(bm >> 10) * FD * FD + (size_t)(bn + l16) * FD;

    floatx4 acc[4] = {};
    #pragma unroll
    for (int k0 = 0; k0 < FD; k0 += 32) {
        const int ko = k0 + q * 8;
        bf16x8 af = cvt8(*(const float4*)&xr[ko], *(const float4*)&xr[ko + 4]);
        #pragma unroll
        for (int nj = 0; nj < 4; nj++) {
            bf16x8 bq = *(const bf16x8*)&g0[(size_t)nj * 16 * FD + ko];
            acc[nj] = __builtin_amdgcn_mfma_f32_16x16x32_bf16(af, bq, acc[nj], 0, 0, 0);
        }
    }

    #pragma unroll
    for (int i = 0; i < 4; i++) {
        const int m = bm + wave * 16 + q * 4 + i;
        float d = dvec[m];
        #pragma unroll
        for (int nj = 0; nj < 4; nj++) {
            const int n = bn + nj * 16 + l16;
            float v = (acc[nj][i] - d * (float)U2[(size_t)m * FD + n]) * (1.0f / 1024.0f);
            out[(size_t)m * FD + n] = v + x[(size_t)m * FD + n];
        }
    }
}

extern "C" void kernel_launch(void* const* d_in, const int* in_sizes, int n_in,
                              void* d_out, int out_size, void* d_ws, size_t ws_size,
                              hipStream_t stream)
{
    const float* x  = (const float*)d_in[0];
    const float* Wa = (const float*)d_in[1];
    const float* Wb = (const float*)d_in[2];
    const float* Wu = (const float*)d_in[3];
    const float* bu = (const float*)d_in[4];
    const float* Wr = (const float*)d_in[5];
    float* out = (float*)d_out;

    char* w = (char*)d_ws;
    bf16* WfC   = (bf16*)w;  w += (size_t)FD * FD * 2;
    bf16* WfA   = (bf16*)w;  w += (size_t)FD * FD * 2;
    float* bc   = (float*)w; w += (size_t)FD * 4;
    bf16* U2    = (bf16*)w;  w += (size_t)RR * FD * 2;
    bf16* abT   = (bf16*)w;  w += (size_t)RR * FD * 2;
    bf16* U2T   = (bf16*)w;  w += (size_t)RR * FD * 2;
    bf16* G     = (bf16*)w;  w += (size_t)NB * FD * FD * 2;
    float* dvec = (float*)w; w += (size_t)RR * 4;

    dim3 blk(256);

    prep<<<dim3(513), blk, 0, stream>>>(Wa, Wb, Wu, bu, Wr, WfC, WfA, bc);

    proj<<<dim3(1024), blk, 0, stream>>>(x, WfA, WfC, U2, abT, U2T, bc, dvec);

    m2_mfma<<<dim3(8, 4, 16), blk, 0, stream>>>(U2T, abT, G);

    final_mfma<<<dim3(4, 256), blk, 0, stream>>>(x, G, dvec, U2, out);
}